// Round 1
// baseline (1587.757 us; speedup 1.0000x reference)
//
#include <hip/hip_runtime.h>
#include <math.h>

// ---------------- graph build ----------------

__global__ void count_kernel(const int* __restrict__ ei, int* __restrict__ cnt, int E) {
    int e = blockIdx.x * 256 + threadIdx.x;
    if (e < E) atomicAdd(&cnt[ei[E + e]], 1);
}

// per-512-chunk exclusive scan of cnt -> colptr (local), block totals -> bsum.
// also computes dinv = rsqrt(cnt+1)
__global__ void scanA_kernel(const int* __restrict__ cnt, float* __restrict__ dinv,
                             int* __restrict__ colptr, int* __restrict__ bsum, int n) {
    __shared__ int s[256];
    int b = blockIdx.x, t = threadIdx.x;
    int i = b * 512 + 2 * t;
    int c0 = (i     < n) ? cnt[i]     : 0;
    int c1 = (i + 1 < n) ? cnt[i + 1] : 0;
    if (i     < n) dinv[i]     = rsqrtf((float)(c0 + 1));
    if (i + 1 < n) dinv[i + 1] = rsqrtf((float)(c1 + 1));
    int v = c0 + c1;
    s[t] = v;
    __syncthreads();
    #pragma unroll
    for (int o = 1; o < 256; o <<= 1) {
        int x = (t >= o) ? s[t - o] : 0;
        __syncthreads();
        s[t] += x;
        __syncthreads();
    }
    int excl = s[t] - v;
    if (i     < n) colptr[i]     = excl;
    if (i + 1 < n) colptr[i + 1] = excl + c0;
    if (t == 255) bsum[b] = s[t];
}

__global__ void scanB_kernel(int* bsum, int nb) {
    __shared__ int s[256];
    int t = threadIdx.x;
    int v = (t < nb) ? bsum[t] : 0;
    s[t] = v;
    __syncthreads();
    #pragma unroll
    for (int o = 1; o < 256; o <<= 1) {
        int x = (t >= o) ? s[t - o] : 0;
        __syncthreads();
        s[t] += x;
        __syncthreads();
    }
    if (t < nb) bsum[t] = s[t] - v;
}

__global__ void scanC_kernel(int* __restrict__ colptr, const int* __restrict__ bsum,
                             int n, int E) {
    int b = blockIdx.x, t = threadIdx.x;
    int off = bsum[b];
    int i = b * 512 + 2 * t;
    if (i     < n) colptr[i]     += off;
    if (i + 1 < n) colptr[i + 1] += off;
    if (b == 0 && t == 0) colptr[n] = E;
}

__global__ void fill_kernel(const int* __restrict__ ei, const int* __restrict__ colptr,
                            int* __restrict__ fillc, int* __restrict__ eidx, int E) {
    int e = blockIdx.x * 256 + threadIdx.x;
    if (e < E) {
        int r = ei[e];
        int c = ei[E + e];
        int pos = colptr[c] + atomicAdd(&fillc[c], 1);
        eidx[pos] = r;
    }
}

// ---------------- layer 1 GEMM: xs = (x @ W1) * dinv[row] ----------------
// M x 512 @ 512 x 256, fp32. 64x64 tile, BK=16, 4x4 micro-tile per thread.

__global__ __launch_bounds__(256) void gemm1_kernel(const float* __restrict__ A,
                                                    const float* __restrict__ B,
                                                    const float* __restrict__ dinv,
                                                    float* __restrict__ C, int M) {
    __shared__ float As[16][68];   // [k][m], stride 68: 16B-aligned rows, 2-way banks (free)
    __shared__ float Bs[16][68];   // [k][n]
    int t = threadIdx.x;
    int m0 = blockIdx.x * 64, n0 = blockIdx.y * 64;
    int tx = t & 15, ty = t >> 4;
    int la_m = t >> 2, la_k = (t & 3) * 4;   // A: float4 along k
    int lb_k = t >> 4, lb_n = (t & 15) * 4;  // B: float4 along n
    int a_m = m0 + la_m; if (a_m >= M) a_m = M - 1;   // clamp (stores guarded)
    const float* Ap = A + (size_t)a_m * 512 + la_k;
    const float* Bp = B + (size_t)lb_k * 256 + n0 + lb_n;
    float acc[4][4];
    #pragma unroll
    for (int i = 0; i < 4; i++)
        #pragma unroll
        for (int j = 0; j < 4; j++) acc[i][j] = 0.f;

    for (int k0 = 0; k0 < 512; k0 += 16) {
        float4 av = *(const float4*)(Ap + k0);
        float4 bv = *(const float4*)(Bp + (size_t)k0 * 256);
        __syncthreads();
        As[la_k + 0][la_m] = av.x;
        As[la_k + 1][la_m] = av.y;
        As[la_k + 2][la_m] = av.z;
        As[la_k + 3][la_m] = av.w;
        *(float4*)&Bs[lb_k][lb_n] = bv;
        __syncthreads();
        #pragma unroll
        for (int kk = 0; kk < 16; kk++) {
            float4 a = *(const float4*)&As[kk][ty * 4];
            float4 b = *(const float4*)&Bs[kk][tx * 4];
            acc[0][0] += a.x * b.x; acc[0][1] += a.x * b.y; acc[0][2] += a.x * b.z; acc[0][3] += a.x * b.w;
            acc[1][0] += a.y * b.x; acc[1][1] += a.y * b.y; acc[1][2] += a.y * b.z; acc[1][3] += a.y * b.w;
            acc[2][0] += a.z * b.x; acc[2][1] += a.z * b.y; acc[2][2] += a.z * b.z; acc[2][3] += a.z * b.w;
            acc[3][0] += a.w * b.x; acc[3][1] += a.w * b.y; acc[3][2] += a.w * b.z; acc[3][3] += a.w * b.w;
        }
    }
    #pragma unroll
    for (int i = 0; i < 4; i++) {
        int m = m0 + ty * 4 + i;
        if (m < M) {
            float d = dinv[m];
            float4 r;
            r.x = acc[i][0] * d; r.y = acc[i][1] * d; r.z = acc[i][2] * d; r.w = acc[i][3] * d;
            *(float4*)&C[(size_t)m * 256 + n0 + tx * 4] = r;
        }
    }
}

// ---------------- layer 1 aggregate: h = relu(dinv[c]*(sum_in xs[r] + xs[c]) + b1) ----

__global__ __launch_bounds__(256) void spmm1_kernel(const float* __restrict__ xs,
                                                    const int* __restrict__ colptr,
                                                    const int* __restrict__ eidx,
                                                    const float* __restrict__ dinv,
                                                    const float* __restrict__ b1,
                                                    float* __restrict__ h) {
    int c = blockIdx.x, t = threadIdx.x;
    float self = xs[(size_t)c * 256 + t];
    int j = colptr[c], jend = colptr[c + 1];
    float a0 = 0.f, a1 = 0.f, a2 = 0.f, a3 = 0.f;
    for (; j + 3 < jend; j += 4) {
        int r0 = eidx[j], r1 = eidx[j + 1], r2 = eidx[j + 2], r3 = eidx[j + 3];
        a0 += xs[(size_t)r0 * 256 + t];
        a1 += xs[(size_t)r1 * 256 + t];
        a2 += xs[(size_t)r2 * 256 + t];
        a3 += xs[(size_t)r3 * 256 + t];
    }
    for (; j < jend; j++) a0 += xs[(size_t)eidx[j] * 256 + t];
    float acc = self + ((a0 + a1) + (a2 + a3));
    float v = acc * dinv[c] + b1[t];
    h[(size_t)c * 256 + t] = fmaxf(v, 0.f);
}

// ---------------- layer 2 GEMM: t2 = (h @ W2) * dinv[row] ----------------
// M x 256 @ 256 x 40. W2 resident in LDS; 8 rows per block-iteration.

__global__ __launch_bounds__(320) void gemm2_kernel(const float* __restrict__ h,
                                                    const float* __restrict__ W2,
                                                    const float* __restrict__ dinv,
                                                    float* __restrict__ t2, int M) {
    __shared__ float w2s[256 * 40];
    __shared__ float hs[8 * 260];   // pad 260: rows land on distinct banks
    int t = threadIdx.x;
    for (int idx = t; idx < 256 * 40; idx += 320) w2s[idx] = W2[idx];
    int r = t / 40, c = t - r * 40;          // 320 = 8 rows x 40 cols
    int ngroups = (M + 7) / 8;
    for (int g = blockIdx.x; g < ngroups; g += gridDim.x) {
        int r0 = g * 8;
        __syncthreads();
        for (int idx = t; idx < 2048; idx += 320) {
            int rr = idx >> 8, k = idx & 255;
            int row = r0 + rr;
            hs[rr * 260 + k] = (row < M) ? h[(size_t)row * 256 + k] : 0.f;
        }
        __syncthreads();
        float acc = 0.f;
        #pragma unroll 8
        for (int k = 0; k < 256; k++) acc += hs[r * 260 + k] * w2s[k * 40 + c];
        int row = r0 + r;
        if (row < M) t2[(size_t)row * 40 + c] = acc * dinv[row];
    }
}

// ---------------- layer 2 aggregate + bias + log_softmax ----------------
// one wave per node; lanes 0..39 hold the 40 class features.

__global__ __launch_bounds__(256) void spmm2_kernel(const float* __restrict__ t2,
                                                    const int* __restrict__ colptr,
                                                    const int* __restrict__ eidx,
                                                    const float* __restrict__ dinv,
                                                    const float* __restrict__ b2,
                                                    float* __restrict__ out, int Nn) {
    int wid = threadIdx.x >> 6, lane = threadIdx.x & 63;
    int c = blockIdx.x * 4 + wid;
    if (c >= Nn) return;                   // wave-uniform
    int f = (lane < 40) ? lane : 0;
    float acc = t2[(size_t)c * 40 + f];    // self message
    int j = colptr[c], jend = colptr[c + 1];
    float a0 = 0.f, a1 = 0.f, a2 = 0.f, a3 = 0.f;
    for (; j + 3 < jend; j += 4) {
        int r0 = eidx[j], r1 = eidx[j + 1], r2 = eidx[j + 2], r3 = eidx[j + 3];
        a0 += t2[(size_t)r0 * 40 + f];
        a1 += t2[(size_t)r1 * 40 + f];
        a2 += t2[(size_t)r2 * 40 + f];
        a3 += t2[(size_t)r3 * 40 + f];
    }
    for (; j < jend; j++) a0 += t2[(size_t)eidx[j] * 40 + f];
    acc += (a0 + a1) + (a2 + a3);
    float val = (lane < 40) ? (acc * dinv[c] + b2[f]) : -INFINITY;
    float m = val;
    #pragma unroll
    for (int o = 32; o > 0; o >>= 1) { float z = __shfl_xor(m, o); m = fmaxf(m, z); }
    float ex = (lane < 40) ? expf(val - m) : 0.f;
    float s = ex;
    #pragma unroll
    for (int o = 32; o > 0; o >>= 1) s += __shfl_xor(s, o);
    if (lane < 40) out[(size_t)c * 40 + lane] = val - m - logf(s);
}

// ---------------- launcher ----------------

extern "C" void kernel_launch(void* const* d_in, const int* in_sizes, int n_in,
                              void* d_out, int out_size, void* d_ws, size_t ws_size,
                              hipStream_t stream) {
    const float* x  = (const float*)d_in[0];
    const int*   ei = (const int*)d_in[1];   // edge_index as int32 [row... | col...]
    const float* W1 = (const float*)d_in[2];
    const float* b1 = (const float*)d_in[3];
    const float* W2 = (const float*)d_in[4];
    const float* b2 = (const float*)d_in[5];
    float* out = (float*)d_out;

    int N = in_sizes[0] / 512;   // 100000
    int E = in_sizes[1] / 2;     // 3200000

    // workspace carve-up (~209 MiB total)
    char* p = (char*)d_ws;
    auto carve = [&](size_t bytes) -> char* {
        char* q = p;
        p += (bytes + 1023) & ~(size_t)1023;
        return q;
    };
    float* dinv   = (float*)carve((size_t)N * 4);
    int*   cnt    = (int*)carve((size_t)N * 4);
    int*   colptr = (int*)carve(((size_t)N + 1) * 4);
    int*   fillc  = (int*)carve((size_t)N * 4);
    int*   bsum   = (int*)carve(1024 * 4);
    int*   eidx   = (int*)carve((size_t)E * 4);
    float* xs     = (float*)carve((size_t)N * 256 * 4);
    float* h      = (float*)carve((size_t)N * 256 * 4);
    float* t2     = xs;   // xs dead after spmm1; reuse for layer-2 activations

    hipMemsetAsync(cnt,   0, (size_t)N * 4, stream);
    hipMemsetAsync(fillc, 0, (size_t)N * 4, stream);

    int eb = (E + 255) / 256;
    int nb = (N + 511) / 512;   // 196 (must be <= 256 for scanB)

    count_kernel<<<eb, 256, 0, stream>>>(ei, cnt, E);
    scanA_kernel<<<nb, 256, 0, stream>>>(cnt, dinv, colptr, bsum, N);
    scanB_kernel<<<1, 256, 0, stream>>>(bsum, nb);
    scanC_kernel<<<nb, 256, 0, stream>>>(colptr, bsum, N, E);
    fill_kernel<<<eb, 256, 0, stream>>>(ei, colptr, fillc, eidx, E);

    dim3 g1((N + 63) / 64, 4);
    gemm1_kernel<<<g1, 256, 0, stream>>>(x, W1, dinv, xs, N);
    spmm1_kernel<<<N, 256, 0, stream>>>(xs, colptr, eidx, dinv, b1, h);
    gemm2_kernel<<<1250, 320, 0, stream>>>(h, W2, dinv, t2, N);
    spmm2_kernel<<<(N + 3) / 4, 256, 0, stream>>>(t2, colptr, eidx, dinv, b2, out, N);
}

// Round 2
// 1088.950 us; speedup vs baseline: 1.4581x; 1.4581x over previous
//
#include <hip/hip_runtime.h>
#include <math.h>

typedef __attribute__((ext_vector_type(8))) short short8;
typedef __attribute__((ext_vector_type(4))) float f32x4;

typedef __attribute__((address_space(1))) const unsigned int guint;
typedef __attribute__((address_space(3))) unsigned int luint;

static __device__ __forceinline__ unsigned short f2bf(float f) {
    unsigned int u = __float_as_uint(f);
    unsigned int r = (u + 0x7FFFu + ((u >> 16) & 1u)) >> 16;
    return (unsigned short)r;
}
static __device__ __forceinline__ float b2f(unsigned short s) {
    return __uint_as_float(((unsigned int)s) << 16);
}

// ---------------- graph build ----------------

__global__ void count_kernel(const int* __restrict__ ei, int* __restrict__ cnt, int E) {
    int e = blockIdx.x * 256 + threadIdx.x;
    if (e < E) atomicAdd(&cnt[ei[E + e]], 1);
}

__global__ void scanA_kernel(const int* __restrict__ cnt, float* __restrict__ dinv,
                             int* __restrict__ colptr, int* __restrict__ bsum, int n) {
    __shared__ int s[256];
    int b = blockIdx.x, t = threadIdx.x;
    int i = b * 512 + 2 * t;
    int c0 = (i     < n) ? cnt[i]     : 0;
    int c1 = (i + 1 < n) ? cnt[i + 1] : 0;
    if (i     < n) dinv[i]     = rsqrtf((float)(c0 + 1));
    if (i + 1 < n) dinv[i + 1] = rsqrtf((float)(c1 + 1));
    int v = c0 + c1;
    s[t] = v;
    __syncthreads();
    #pragma unroll
    for (int o = 1; o < 256; o <<= 1) {
        int x = (t >= o) ? s[t - o] : 0;
        __syncthreads();
        s[t] += x;
        __syncthreads();
    }
    int excl = s[t] - v;
    if (i     < n) colptr[i]     = excl;
    if (i + 1 < n) colptr[i + 1] = excl + c0;
    if (t == 255) bsum[b] = s[t];
}

__global__ void scanB_kernel(int* bsum, int nb) {
    __shared__ int s[256];
    int t = threadIdx.x;
    int v = (t < nb) ? bsum[t] : 0;
    s[t] = v;
    __syncthreads();
    #pragma unroll
    for (int o = 1; o < 256; o <<= 1) {
        int x = (t >= o) ? s[t - o] : 0;
        __syncthreads();
        s[t] += x;
        __syncthreads();
    }
    if (t < nb) bsum[t] = s[t] - v;
}

__global__ void scanC_kernel(int* __restrict__ colptr, const int* __restrict__ bsum,
                             int n, int E) {
    int b = blockIdx.x, t = threadIdx.x;
    int off = bsum[b];
    int i = b * 512 + 2 * t;
    if (i     < n) colptr[i]     += off;
    if (i + 1 < n) colptr[i + 1] += off;
    if (b == 0 && t == 0) colptr[n] = E;
}

__global__ void fill_kernel(const int* __restrict__ ei, const int* __restrict__ colptr,
                            int* __restrict__ fillc, int* __restrict__ eidx, int E) {
    int e = blockIdx.x * 256 + threadIdx.x;
    if (e < E) {
        int r = ei[e];
        int c = ei[E + e];
        int pos = colptr[c] + atomicAdd(&fillc[c], 1);
        eidx[pos] = r;
    }
}

// ---------------- dtype conversion ----------------

// x (fp32, valid elems) -> xb (bf16, total elems incl. zero pad rows)
__global__ void convert_x_kernel(const float* __restrict__ x, unsigned short* __restrict__ xb,
                                 long valid, long total) {
    long off = ((long)blockIdx.x * 256 + threadIdx.x) * 4;
    if (off >= total) return;
    float4 v = make_float4(0.f, 0.f, 0.f, 0.f);
    if (off < valid) v = *(const float4*)(x + off);
    uint2 p;
    p.x = (unsigned int)f2bf(v.x) | ((unsigned int)f2bf(v.y) << 16);
    p.y = (unsigned int)f2bf(v.z) | ((unsigned int)f2bf(v.w) << 16);
    *(uint2*)(xb + off) = p;
}

// W1 [512][256] fp32 -> w1t [256][512] bf16 (transposed)
__global__ void convert_w1_kernel(const float* __restrict__ W1, unsigned short* __restrict__ w1t) {
    int id = blockIdx.x * 256 + threadIdx.x;   // 512*256 = 131072
    int k = id >> 8, n = id & 255;
    w1t[(size_t)n * 512 + k] = f2bf(W1[id]);
}

// ---------------- layer 1 GEMM (bf16 MFMA): xs = bf16((xb @ W1) * dinv[row]) --------
// 128x128 tile, BK=32, 4 waves, each wave 64x64 via 4x4 of 16x16x32 MFMA.
// m97 structure: global_load_lds width-16 staging, 2-barrier K-loop.

__global__ __launch_bounds__(256) void gemm1_kernel(const unsigned short* __restrict__ xb,
                                                    const unsigned short* __restrict__ w1t,
                                                    const float* __restrict__ dinv,
                                                    unsigned short* __restrict__ xs, int M) {
    __shared__ short As[128 * 32];   // [m][k] row-major, contiguous (glds requires no pad)
    __shared__ short Bs[128 * 32];   // [n][k] row-major (W1 pre-transposed)
    int t = threadIdx.x;
    int m0 = blockIdx.x * 128, n0 = blockIdx.y * 128;
    int lane = t & 63, wv = t >> 6;
    int wm = (wv & 1) * 64, wn = (wv >> 1) * 64;
    int lm = lane & 15, q = lane >> 4;

    // staging: 512 chunks of 16B per buffer; thread t handles chunks t and t+256
    int am0 = t >> 2, ak = (t & 3) * 8;
    const unsigned short* Ag0 = xb  + (size_t)(m0 + am0) * 512 + ak;
    const unsigned short* Ag1 = xb  + (size_t)(m0 + am0 + 64) * 512 + ak;
    const unsigned short* Bg0 = w1t + (size_t)(n0 + am0) * 512 + ak;
    const unsigned short* Bg1 = w1t + (size_t)(n0 + am0 + 64) * 512 + ak;
    short* Al0 = As + t * 8;
    short* Al1 = As + t * 8 + 2048;
    short* Bl0 = Bs + t * 8;
    short* Bl1 = Bs + t * 8 + 2048;

    f32x4 acc[4][4];
    f32x4 z = {0.f, 0.f, 0.f, 0.f};
    #pragma unroll
    for (int i = 0; i < 4; i++)
        #pragma unroll
        for (int j = 0; j < 4; j++) acc[i][j] = z;

    for (int k0 = 0; k0 < 512; k0 += 32) {
        __syncthreads();
        __builtin_amdgcn_global_load_lds((guint*)(Ag0 + k0), (luint*)Al0, 16, 0, 0);
        __builtin_amdgcn_global_load_lds((guint*)(Ag1 + k0), (luint*)Al1, 16, 0, 0);
        __builtin_amdgcn_global_load_lds((guint*)(Bg0 + k0), (luint*)Bl0, 16, 0, 0);
        __builtin_amdgcn_global_load_lds((guint*)(Bg1 + k0), (luint*)Bl1, 16, 0, 0);
        __syncthreads();
        short8 af[4], bf[4];
        #pragma unroll
        for (int i = 0; i < 4; i++)
            af[i] = *(const short8*)(As + (wm + i * 16 + lm) * 32 + q * 8);
        #pragma unroll
        for (int j = 0; j < 4; j++)
            bf[j] = *(const short8*)(Bs + (wn + j * 16 + lm) * 32 + q * 8);
        #pragma unroll
        for (int i = 0; i < 4; i++)
            #pragma unroll
            for (int j = 0; j < 4; j++)
                acc[i][j] = __builtin_amdgcn_mfma_f32_16x16x32_bf16(af[i], bf[j], acc[i][j], 0, 0, 0);
    }

    #pragma unroll
    for (int i = 0; i < 4; i++) {
        #pragma unroll
        for (int r = 0; r < 4; r++) {
            int m = m0 + wm + i * 16 + q * 4 + r;
            if (m < M) {
                float d = dinv[m];
                #pragma unroll
                for (int j = 0; j < 4; j++) {
                    int n = n0 + wn + j * 16 + lm;
                    xs[(size_t)m * 256 + n] = f2bf(acc[i][j][r] * d);
                }
            }
        }
    }
}

// ---------------- layer 1 aggregate: h = bf16(relu(dinv[c]*(sum_in xs[r] + xs[c]) + b1))
// one wave per node; lane handles 4 features via one 8B (uint2) load per row.

__global__ __launch_bounds__(256) void spmm1_kernel(const unsigned short* __restrict__ xs,
                                                    const int* __restrict__ colptr,
                                                    const int* __restrict__ eidx,
                                                    const float* __restrict__ dinv,
                                                    const float* __restrict__ b1,
                                                    unsigned short* __restrict__ h, int Nn) {
    int wid = threadIdx.x >> 6, lane = threadIdx.x & 63;
    int c = blockIdx.x * 4 + wid;
    if (c >= Nn) return;
    const uint2* base = (const uint2*)xs;   // row r = 64 uint2 chunks
    uint2 sv = base[(size_t)c * 64 + lane];
    float a0 = b2f((unsigned short)(sv.x & 0xFFFF));
    float a1 = __uint_as_float(sv.x & 0xFFFF0000u);
    float a2 = b2f((unsigned short)(sv.y & 0xFFFF));
    float a3 = __uint_as_float(sv.y & 0xFFFF0000u);
    int j = colptr[c], jend = colptr[c + 1];
    for (; j + 3 < jend; j += 4) {
        int r0 = eidx[j], r1 = eidx[j + 1], r2 = eidx[j + 2], r3 = eidx[j + 3];
        uint2 v0 = base[(size_t)r0 * 64 + lane];
        uint2 v1 = base[(size_t)r1 * 64 + lane];
        uint2 v2 = base[(size_t)r2 * 64 + lane];
        uint2 v3 = base[(size_t)r3 * 64 + lane];
        a0 += __uint_as_float(v0.x << 16) + __uint_as_float(v1.x << 16)
            + __uint_as_float(v2.x << 16) + __uint_as_float(v3.x << 16);
        a1 += __uint_as_float(v0.x & 0xFFFF0000u) + __uint_as_float(v1.x & 0xFFFF0000u)
            + __uint_as_float(v2.x & 0xFFFF0000u) + __uint_as_float(v3.x & 0xFFFF0000u);
        a2 += __uint_as_float(v0.y << 16) + __uint_as_float(v1.y << 16)
            + __uint_as_float(v2.y << 16) + __uint_as_float(v3.y << 16);
        a3 += __uint_as_float(v0.y & 0xFFFF0000u) + __uint_as_float(v1.y & 0xFFFF0000u)
            + __uint_as_float(v2.y & 0xFFFF0000u) + __uint_as_float(v3.y & 0xFFFF0000u);
    }
    for (; j < jend; j++) {
        uint2 v0 = base[(size_t)eidx[j] * 64 + lane];
        a0 += __uint_as_float(v0.x << 16);
        a1 += __uint_as_float(v0.x & 0xFFFF0000u);
        a2 += __uint_as_float(v0.y << 16);
        a3 += __uint_as_float(v0.y & 0xFFFF0000u);
    }
    float d = dinv[c];
    float4 bb = ((const float4*)b1)[lane];
    float f0 = fmaxf(a0 * d + bb.x, 0.f);
    float f1 = fmaxf(a1 * d + bb.y, 0.f);
    float f2 = fmaxf(a2 * d + bb.z, 0.f);
    float f3 = fmaxf(a3 * d + bb.w, 0.f);
    uint2 p;
    p.x = (unsigned int)f2bf(f0) | ((unsigned int)f2bf(f1) << 16);
    p.y = (unsigned int)f2bf(f2) | ((unsigned int)f2bf(f3) << 16);
    *(uint2*)(h + (size_t)c * 256 + 4 * lane) = p;
}

// ---------------- layer 2 GEMM: t2 = bf16((h @ W2) * dinv[row]) ----------------
// W2 (fp32) in LDS; 32 rows/block; 4 rows per thread with float4 LDS reads.

__global__ __launch_bounds__(320) void gemm2_kernel(const unsigned short* __restrict__ h,
                                                    const float* __restrict__ W2,
                                                    const float* __restrict__ dinv,
                                                    unsigned short* __restrict__ t2, int M) {
    __shared__ float w2s[256 * 40];   // [k][c], 40 KB
    __shared__ float hs[32][260];     // 33.3 KB, padded
    int t = threadIdx.x;
    for (int idx = t; idx < 10240; idx += 320) w2s[idx] = W2[idx];
    int r0g = blockIdx.x * 32;
    for (int idx = t; idx < 2048; idx += 320) {   // 2048 chunks of 4 elems
        int rr = idx >> 6, k4 = (idx & 63) * 4;
        int row = r0g + rr;
        float4 v = make_float4(0.f, 0.f, 0.f, 0.f);
        if (row < M) {
            uint2 u = *(const uint2*)(h + (size_t)row * 256 + k4);
            v.x = __uint_as_float(u.x << 16);
            v.y = __uint_as_float(u.x & 0xFFFF0000u);
            v.z = __uint_as_float(u.y << 16);
            v.w = __uint_as_float(u.y & 0xFFFF0000u);
        }
        *(float4*)&hs[rr][k4] = v;
    }
    __syncthreads();
    int c = t % 40, rb = (t / 40) * 4;   // 8 groups x 4 rows = 32 rows
    float a0 = 0.f, a1 = 0.f, a2 = 0.f, a3 = 0.f;
    #pragma unroll 2
    for (int k = 0; k < 256; k += 4) {
        float4 h0 = *(const float4*)&hs[rb + 0][k];
        float4 h1 = *(const float4*)&hs[rb + 1][k];
        float4 h2 = *(const float4*)&hs[rb + 2][k];
        float4 h3 = *(const float4*)&hs[rb + 3][k];
        float w0 = w2s[(k + 0) * 40 + c];
        float w1 = w2s[(k + 1) * 40 + c];
        float w2 = w2s[(k + 2) * 40 + c];
        float w3 = w2s[(k + 3) * 40 + c];
        a0 += h0.x * w0 + h0.y * w1 + h0.z * w2 + h0.w * w3;
        a1 += h1.x * w0 + h1.y * w1 + h1.z * w2 + h1.w * w3;
        a2 += h2.x * w0 + h2.y * w1 + h2.z * w2 + h2.w * w3;
        a3 += h3.x * w0 + h3.y * w1 + h3.z * w2 + h3.w * w3;
    }
    int row = r0g + rb;
    if (row + 0 < M) t2[(size_t)(row + 0) * 40 + c] = f2bf(a0 * dinv[row + 0]);
    if (row + 1 < M) t2[(size_t)(row + 1) * 40 + c] = f2bf(a1 * dinv[row + 1]);
    if (row + 2 < M) t2[(size_t)(row + 2) * 40 + c] = f2bf(a2 * dinv[row + 2]);
    if (row + 3 < M) t2[(size_t)(row + 3) * 40 + c] = f2bf(a3 * dinv[row + 3]);
}

// ---------------- layer 2 aggregate + bias + log_softmax ----------------

__global__ __launch_bounds__(256) void spmm2_kernel(const unsigned short* __restrict__ t2,
                                                    const int* __restrict__ colptr,
                                                    const int* __restrict__ eidx,
                                                    const float* __restrict__ dinv,
                                                    const float* __restrict__ b2,
                                                    float* __restrict__ out, int Nn) {
    int wid = threadIdx.x >> 6, lane = threadIdx.x & 63;
    int c = blockIdx.x * 4 + wid;
    if (c >= Nn) return;
    int f = (lane < 40) ? lane : 0;
    float acc = b2f(t2[(size_t)c * 40 + f]);   // self message
    int j = colptr[c], jend = colptr[c + 1];
    float a0 = 0.f, a1 = 0.f, a2 = 0.f, a3 = 0.f;
    for (; j + 3 < jend; j += 4) {
        int r0 = eidx[j], r1 = eidx[j + 1], r2 = eidx[j + 2], r3 = eidx[j + 3];
        a0 += b2f(t2[(size_t)r0 * 40 + f]);
        a1 += b2f(t2[(size_t)r1 * 40 + f]);
        a2 += b2f(t2[(size_t)r2 * 40 + f]);
        a3 += b2f(t2[(size_t)r3 * 40 + f]);
    }
    for (; j < jend; j++) a0 += b2f(t2[(size_t)eidx[j] * 40 + f]);
    acc += (a0 + a1) + (a2 + a3);
    float val = (lane < 40) ? (acc * dinv[c] + b2[f]) : -INFINITY;
    float m = val;
    #pragma unroll
    for (int o = 32; o > 0; o >>= 1) { float z = __shfl_xor(m, o); m = fmaxf(m, z); }
    float ex = (lane < 40) ? expf(val - m) : 0.f;
    float s = ex;
    #pragma unroll
    for (int o = 32; o > 0; o >>= 1) s += __shfl_xor(s, o);
    if (lane < 40) out[(size_t)c * 40 + lane] = val - m - logf(s);
}

// ---------------- launcher ----------------

extern "C" void kernel_launch(void* const* d_in, const int* in_sizes, int n_in,
                              void* d_out, int out_size, void* d_ws, size_t ws_size,
                              hipStream_t stream) {
    const float* x  = (const float*)d_in[0];
    const int*   ei = (const int*)d_in[1];
    const float* W1 = (const float*)d_in[2];
    const float* b1 = (const float*)d_in[3];
    const float* W2 = (const float*)d_in[4];
    const float* b2 = (const float*)d_in[5];
    float* out = (float*)d_out;

    int N = in_sizes[0] / 512;   // 100000
    int E = in_sizes[1] / 2;     // 3200000
    int Mpad = ((N + 127) / 128) * 128;   // 100096

    char* p = (char*)d_ws;
    auto carve = [&](size_t bytes) -> char* {
        char* q = p;
        p += (bytes + 1023) & ~(size_t)1023;
        return q;
    };
    float* dinv   = (float*)carve((size_t)N * 4);
    int*   cnt    = (int*)carve((size_t)N * 4);
    int*   colptr = (int*)carve(((size_t)N + 1) * 4);
    int*   fillc  = (int*)carve((size_t)N * 4);
    int*   bsum   = (int*)carve(1024 * 4);
    int*   eidx   = (int*)carve((size_t)E * 4);
    unsigned short* w1t = (unsigned short*)carve((size_t)256 * 512 * 2);
    unsigned short* xb  = (unsigned short*)carve((size_t)Mpad * 512 * 2);  // 102.6 MB
    unsigned short* xs  = (unsigned short*)carve((size_t)Mpad * 256 * 2);  //  51.3 MB
    // alias: xb region is dead after gemm1 → reuse for h and t2
    unsigned short* h  = xb;                                   // N*256 bf16 (51.2 MB)
    unsigned short* t2 = xb + (size_t)Mpad * 256;              // N*40 bf16 (8 MB)

    hipMemsetAsync(cnt,   0, (size_t)N * 4, stream);
    hipMemsetAsync(fillc, 0, (size_t)N * 4, stream);

    int eb = (E + 255) / 256;
    int nb = (N + 511) / 512;

    count_kernel<<<eb, 256, 0, stream>>>(ei, cnt, E);
    scanA_kernel<<<nb, 256, 0, stream>>>(cnt, dinv, colptr, bsum, N);
    scanB_kernel<<<1, 256, 0, stream>>>(bsum, nb);
    scanC_kernel<<<nb, 256, 0, stream>>>(colptr, bsum, N, E);
    fill_kernel<<<eb, 256, 0, stream>>>(ei, colptr, fillc, eidx, E);

    long totalx = (long)Mpad * 512;
    long validx = (long)N * 512;
    convert_x_kernel<<<(int)((totalx / 4 + 255) / 256), 256, 0, stream>>>(x, xb, validx, totalx);
    convert_w1_kernel<<<512, 256, 0, stream>>>(W1, w1t);

    dim3 g1(Mpad / 128, 2);
    gemm1_kernel<<<g1, 256, 0, stream>>>(xb, w1t, dinv, xs, N);
    spmm1_kernel<<<(N + 3) / 4, 256, 0, stream>>>(xs, colptr, eidx, dinv, b1, h, N);
    gemm2_kernel<<<(N + 31) / 32, 320, 0, stream>>>(h, W2, dinv, t2, N);
    spmm2_kernel<<<(N + 3) / 4, 256, 0, stream>>>(t2, colptr, eidx, dinv, b2, out, N);
}

// Round 3
// 1050.343 us; speedup vs baseline: 1.5117x; 1.0368x over previous
//
#include <hip/hip_runtime.h>
#include <math.h>

typedef __attribute__((ext_vector_type(8))) short short8;
typedef __attribute__((ext_vector_type(4))) float f32x4;

static __device__ __forceinline__ unsigned short f2bf(float f) {
    unsigned int u = __float_as_uint(f);
    unsigned int r = (u + 0x7FFFu + ((u >> 16) & 1u)) >> 16;
    return (unsigned short)r;
}
static __device__ __forceinline__ float b2f(unsigned short s) {
    return __uint_as_float(((unsigned int)s) << 16);
}

// ---------------- graph build ----------------

__global__ void count_kernel(const int* __restrict__ ei, int* __restrict__ cnt, int E) {
    int e = blockIdx.x * 256 + threadIdx.x;
    if (e < E) atomicAdd(&cnt[ei[E + e]], 1);
}

__global__ void scanA_kernel(const int* __restrict__ cnt, float* __restrict__ dinv,
                             int* __restrict__ colptr, int* __restrict__ bsum, int n) {
    __shared__ int s[256];
    int b = blockIdx.x, t = threadIdx.x;
    int i = b * 512 + 2 * t;
    int c0 = (i     < n) ? cnt[i]     : 0;
    int c1 = (i + 1 < n) ? cnt[i + 1] : 0;
    if (i     < n) dinv[i]     = rsqrtf((float)(c0 + 1));
    if (i + 1 < n) dinv[i + 1] = rsqrtf((float)(c1 + 1));
    int v = c0 + c1;
    s[t] = v;
    __syncthreads();
    #pragma unroll
    for (int o = 1; o < 256; o <<= 1) {
        int x = (t >= o) ? s[t - o] : 0;
        __syncthreads();
        s[t] += x;
        __syncthreads();
    }
    int excl = s[t] - v;
    if (i     < n) colptr[i]     = excl;
    if (i + 1 < n) colptr[i + 1] = excl + c0;
    if (t == 255) bsum[b] = s[t];
}

__global__ void scanB_kernel(int* bsum, int nb) {
    __shared__ int s[256];
    int t = threadIdx.x;
    int v = (t < nb) ? bsum[t] : 0;
    s[t] = v;
    __syncthreads();
    #pragma unroll
    for (int o = 1; o < 256; o <<= 1) {
        int x = (t >= o) ? s[t - o] : 0;
        __syncthreads();
        s[t] += x;
        __syncthreads();
    }
    if (t < nb) bsum[t] = s[t] - v;
}

__global__ void scanC_kernel(int* __restrict__ colptr, const int* __restrict__ bsum,
                             int n, int E) {
    int b = blockIdx.x, t = threadIdx.x;
    int off = bsum[b];
    int i = b * 512 + 2 * t;
    if (i     < n) colptr[i]     += off;
    if (i + 1 < n) colptr[i + 1] += off;
    if (b == 0 && t == 0) colptr[n] = E;
}

__global__ void fill_kernel(const int* __restrict__ ei, const int* __restrict__ colptr,
                            int* __restrict__ fillc, int* __restrict__ eidx, int E) {
    int e = blockIdx.x * 256 + threadIdx.x;
    if (e < E) {
        int r = ei[e];
        int c = ei[E + e];
        int pos = colptr[c] + atomicAdd(&fillc[c], 1);
        eidx[pos] = r;
    }
}

// W1 [512][256] fp32 -> w1t [256][512] bf16 (transposed)
__global__ void convert_w1_kernel(const float* __restrict__ W1, unsigned short* __restrict__ w1t) {
    int id = blockIdx.x * 256 + threadIdx.x;   // 512*256
    int k = id >> 8, n = id & 255;
    w1t[(size_t)n * 512 + k] = f2bf(W1[id]);
}

// ---------------- layer 1 GEMM (bf16 MFMA, fused fp32->bf16 conversion) --------
// xs = bf16((x @ W1) * dinv[row]).  Tile 64x256 (full N), BK=32, 4 waves,
// each wave 64x64 via 4x4 of 16x16x32 MFMA. LDS rows padded to 40 bf16:
// bank pattern (lm*20+q*4)%32 = exact 2-way aliasing = free.

__global__ __launch_bounds__(256) void gemm1_kernel(const float* __restrict__ x,
                                                    const unsigned short* __restrict__ w1t,
                                                    const float* __restrict__ dinv,
                                                    unsigned short* __restrict__ xs, int M) {
    __shared__ unsigned short As[64 * 40];    // [m][k] padded
    __shared__ unsigned short Bs[256 * 40];   // [n][k] padded
    int t = threadIdx.x;
    int m0 = blockIdx.x * 64;
    int lane = t & 63, wv = t >> 6;
    int wn = wv * 64;
    int lm = lane & 15, q = lane >> 4;

    int ra = t >> 2, kc = (t & 3) * 8;   // A: row ra (0..63), k-chunk kc (8 elems)
    int am = m0 + ra; if (am >= M) am = M - 1;
    const float* Ap = x + (size_t)am * 512 + kc;
    const unsigned short* Bp = w1t + (size_t)ra * 512 + kc;   // B rows ra, ra+64, ra+128, ra+192

    f32x4 acc[4][4];
    f32x4 z = {0.f, 0.f, 0.f, 0.f};
    #pragma unroll
    for (int i = 0; i < 4; i++)
        #pragma unroll
        for (int j = 0; j < 4; j++) acc[i][j] = z;

    for (int k0 = 0; k0 < 512; k0 += 32) {
        float4 a0 = *(const float4*)(Ap + k0);
        float4 a1 = *(const float4*)(Ap + k0 + 4);
        uint4 b0 = *(const uint4*)(Bp + k0);
        uint4 b1 = *(const uint4*)(Bp + k0 + 64 * 512);
        uint4 b2 = *(const uint4*)(Bp + k0 + 128 * 512);
        uint4 b3 = *(const uint4*)(Bp + k0 + 192 * 512);
        __syncthreads();   // previous iteration's fragment reads complete
        uint4 ap;
        ap.x = (unsigned int)f2bf(a0.x) | ((unsigned int)f2bf(a0.y) << 16);
        ap.y = (unsigned int)f2bf(a0.z) | ((unsigned int)f2bf(a0.w) << 16);
        ap.z = (unsigned int)f2bf(a1.x) | ((unsigned int)f2bf(a1.y) << 16);
        ap.w = (unsigned int)f2bf(a1.z) | ((unsigned int)f2bf(a1.w) << 16);
        *(uint4*)&As[ra * 40 + kc] = ap;
        *(uint4*)&Bs[(ra +   0) * 40 + kc] = b0;
        *(uint4*)&Bs[(ra +  64) * 40 + kc] = b1;
        *(uint4*)&Bs[(ra + 128) * 40 + kc] = b2;
        *(uint4*)&Bs[(ra + 192) * 40 + kc] = b3;
        __syncthreads();
        short8 af[4], bfr[4];
        #pragma unroll
        for (int i = 0; i < 4; i++)
            af[i] = *(const short8*)&As[(i * 16 + lm) * 40 + q * 8];
        #pragma unroll
        for (int j = 0; j < 4; j++)
            bfr[j] = *(const short8*)&Bs[(wn + j * 16 + lm) * 40 + q * 8];
        #pragma unroll
        for (int i = 0; i < 4; i++)
            #pragma unroll
            for (int j = 0; j < 4; j++)
                acc[i][j] = __builtin_amdgcn_mfma_f32_16x16x32_bf16(af[i], bfr[j], acc[i][j], 0, 0, 0);
    }

    #pragma unroll
    for (int i = 0; i < 4; i++) {
        #pragma unroll
        for (int r = 0; r < 4; r++) {
            int m = m0 + i * 16 + q * 4 + r;
            if (m < M) {
                float d = dinv[m];
                #pragma unroll
                for (int j = 0; j < 4; j++) {
                    int n = wn + j * 16 + lm;
                    xs[(size_t)m * 256 + n] = f2bf(acc[i][j][r] * d);
                }
            }
        }
    }
}

// ---------------- layer 1 aggregate: h = bf16(relu(dinv[c]*(sum_in xs[r] + xs[c]) + b1))
// one wave per node; lane handles 4 features (8B load per gathered row); unroll 8.

__global__ __launch_bounds__(256) void spmm1_kernel(const unsigned short* __restrict__ xs,
                                                    const int* __restrict__ colptr,
                                                    const int* __restrict__ eidx,
                                                    const float* __restrict__ dinv,
                                                    const float* __restrict__ b1,
                                                    unsigned short* __restrict__ h, int Nn) {
    int wid = threadIdx.x >> 6, lane = threadIdx.x & 63;
    int c = blockIdx.x * 4 + wid;
    if (c >= Nn) return;
    const uint2* base = (const uint2*)xs;   // row r = 64 uint2 chunks
    uint2 sv = base[(size_t)c * 64 + lane];
    float a0 = __uint_as_float(sv.x << 16);
    float a1 = __uint_as_float(sv.x & 0xFFFF0000u);
    float a2 = __uint_as_float(sv.y << 16);
    float a3 = __uint_as_float(sv.y & 0xFFFF0000u);
    int j = colptr[c], jend = colptr[c + 1];
    for (; j + 7 < jend; j += 8) {
        uint2 v0 = base[(size_t)eidx[j    ] * 64 + lane];
        uint2 v1 = base[(size_t)eidx[j + 1] * 64 + lane];
        uint2 v2 = base[(size_t)eidx[j + 2] * 64 + lane];
        uint2 v3 = base[(size_t)eidx[j + 3] * 64 + lane];
        uint2 v4 = base[(size_t)eidx[j + 4] * 64 + lane];
        uint2 v5 = base[(size_t)eidx[j + 5] * 64 + lane];
        uint2 v6 = base[(size_t)eidx[j + 6] * 64 + lane];
        uint2 v7 = base[(size_t)eidx[j + 7] * 64 + lane];
        a0 += __uint_as_float(v0.x << 16) + __uint_as_float(v1.x << 16)
            + __uint_as_float(v2.x << 16) + __uint_as_float(v3.x << 16)
            + __uint_as_float(v4.x << 16) + __uint_as_float(v5.x << 16)
            + __uint_as_float(v6.x << 16) + __uint_as_float(v7.x << 16);
        a1 += __uint_as_float(v0.x & 0xFFFF0000u) + __uint_as_float(v1.x & 0xFFFF0000u)
            + __uint_as_float(v2.x & 0xFFFF0000u) + __uint_as_float(v3.x & 0xFFFF0000u)
            + __uint_as_float(v4.x & 0xFFFF0000u) + __uint_as_float(v5.x & 0xFFFF0000u)
            + __uint_as_float(v6.x & 0xFFFF0000u) + __uint_as_float(v7.x & 0xFFFF0000u);
        a2 += __uint_as_float(v0.y << 16) + __uint_as_float(v1.y << 16)
            + __uint_as_float(v2.y << 16) + __uint_as_float(v3.y << 16)
            + __uint_as_float(v4.y << 16) + __uint_as_float(v5.y << 16)
            + __uint_as_float(v6.y << 16) + __uint_as_float(v7.y << 16);
        a3 += __uint_as_float(v0.y & 0xFFFF0000u) + __uint_as_float(v1.y & 0xFFFF0000u)
            + __uint_as_float(v2.y & 0xFFFF0000u) + __uint_as_float(v3.y & 0xFFFF0000u)
            + __uint_as_float(v4.y & 0xFFFF0000u) + __uint_as_float(v5.y & 0xFFFF0000u)
            + __uint_as_float(v6.y & 0xFFFF0000u) + __uint_as_float(v7.y & 0xFFFF0000u);
    }
    for (; j < jend; j++) {
        uint2 v0 = base[(size_t)eidx[j] * 64 + lane];
        a0 += __uint_as_float(v0.x << 16);
        a1 += __uint_as_float(v0.x & 0xFFFF0000u);
        a2 += __uint_as_float(v0.y << 16);
        a3 += __uint_as_float(v0.y & 0xFFFF0000u);
    }
    float d = dinv[c];
    float4 bb = ((const float4*)b1)[lane];
    float f0 = fmaxf(a0 * d + bb.x, 0.f);
    float f1 = fmaxf(a1 * d + bb.y, 0.f);
    float f2 = fmaxf(a2 * d + bb.z, 0.f);
    float f3 = fmaxf(a3 * d + bb.w, 0.f);
    uint2 p;
    p.x = (unsigned int)f2bf(f0) | ((unsigned int)f2bf(f1) << 16);
    p.y = (unsigned int)f2bf(f2) | ((unsigned int)f2bf(f3) << 16);
    *(uint2*)(h + (size_t)c * 256 + 4 * lane) = p;
}

// ---------------- layer 2 GEMM: t2p = bf16((h @ W2) * dinv[row]), row stride 64 ----

__global__ __launch_bounds__(320) void gemm2_kernel(const unsigned short* __restrict__ h,
                                                    const float* __restrict__ W2,
                                                    const float* __restrict__ dinv,
                                                    unsigned short* __restrict__ t2p, int M) {
    __shared__ float w2s[256 * 40];   // [k][c]
    __shared__ float hs[32][260];
    int t = threadIdx.x;
    for (int idx = t; idx < 10240; idx += 320) w2s[idx] = W2[idx];
    int r0g = blockIdx.x * 32;
    for (int idx = t; idx < 2048; idx += 320) {
        int rr = idx >> 6, k4 = (idx & 63) * 4;
        int row = r0g + rr;
        float4 v = make_float4(0.f, 0.f, 0.f, 0.f);
        if (row < M) {
            uint2 u = *(const uint2*)(h + (size_t)row * 256 + k4);
            v.x = __uint_as_float(u.x << 16);
            v.y = __uint_as_float(u.x & 0xFFFF0000u);
            v.z = __uint_as_float(u.y << 16);
            v.w = __uint_as_float(u.y & 0xFFFF0000u);
        }
        *(float4*)&hs[rr][k4] = v;
    }
    __syncthreads();
    int c = t % 40, rb = (t / 40) * 4;
    float a0 = 0.f, a1 = 0.f, a2 = 0.f, a3 = 0.f;
    #pragma unroll 2
    for (int k = 0; k < 256; k += 4) {
        float4 h0 = *(const float4*)&hs[rb + 0][k];
        float4 h1 = *(const float4*)&hs[rb + 1][k];
        float4 h2 = *(const float4*)&hs[rb + 2][k];
        float4 h3 = *(const float4*)&hs[rb + 3][k];
        float w0 = w2s[(k + 0) * 40 + c];
        float w1 = w2s[(k + 1) * 40 + c];
        float w2 = w2s[(k + 2) * 40 + c];
        float w3 = w2s[(k + 3) * 40 + c];
        a0 += h0.x * w0 + h0.y * w1 + h0.z * w2 + h0.w * w3;
        a1 += h1.x * w0 + h1.y * w1 + h1.z * w2 + h1.w * w3;
        a2 += h2.x * w0 + h2.y * w1 + h2.z * w2 + h2.w * w3;
        a3 += h3.x * w0 + h3.y * w1 + h3.z * w2 + h3.w * w3;
    }
    int row = r0g + rb;
    if (row + 0 < M) t2p[(size_t)(row + 0) * 64 + c] = f2bf(a0 * dinv[row + 0]);
    if (row + 1 < M) t2p[(size_t)(row + 1) * 64 + c] = f2bf(a1 * dinv[row + 1]);
    if (row + 2 < M) t2p[(size_t)(row + 2) * 64 + c] = f2bf(a2 * dinv[row + 2]);
    if (row + 3 < M) t2p[(size_t)(row + 3) * 64 + c] = f2bf(a3 * dinv[row + 3]);
}

// ---------------- layer 2 aggregate + bias + log_softmax ----------------
// t2p rows are 128B-aligned cache lines; all 64 lanes load, lanes>=40 masked.

__global__ __launch_bounds__(256) void spmm2_kernel(const unsigned short* __restrict__ t2p,
                                                    const int* __restrict__ colptr,
                                                    const int* __restrict__ eidx,
                                                    const float* __restrict__ dinv,
                                                    const float* __restrict__ b2,
                                                    float* __restrict__ out, int Nn) {
    int wid = threadIdx.x >> 6, lane = threadIdx.x & 63;
    int c = blockIdx.x * 4 + wid;
    if (c >= Nn) return;
    float acc = b2f(t2p[(size_t)c * 64 + lane]);   // self (pad lanes garbage, masked)
    int j = colptr[c], jend = colptr[c + 1];
    float a0 = 0.f, a1 = 0.f, a2 = 0.f, a3 = 0.f;
    for (; j + 7 < jend; j += 8) {
        float u0 = b2f(t2p[(size_t)eidx[j    ] * 64 + lane]);
        float u1 = b2f(t2p[(size_t)eidx[j + 1] * 64 + lane]);
        float u2 = b2f(t2p[(size_t)eidx[j + 2] * 64 + lane]);
        float u3 = b2f(t2p[(size_t)eidx[j + 3] * 64 + lane]);
        float u4 = b2f(t2p[(size_t)eidx[j + 4] * 64 + lane]);
        float u5 = b2f(t2p[(size_t)eidx[j + 5] * 64 + lane]);
        float u6 = b2f(t2p[(size_t)eidx[j + 6] * 64 + lane]);
        float u7 = b2f(t2p[(size_t)eidx[j + 7] * 64 + lane]);
        a0 += u0 + u4; a1 += u1 + u5; a2 += u2 + u6; a3 += u3 + u7;
    }
    for (; j < jend; j++) a0 += b2f(t2p[(size_t)eidx[j] * 64 + lane]);
    acc += (a0 + a1) + (a2 + a3);
    float val = (lane < 40) ? (acc * dinv[c] + b2[lane]) : -INFINITY;
    float m = val;
    #pragma unroll
    for (int o = 32; o > 0; o >>= 1) { float z = __shfl_xor(m, o); m = fmaxf(m, z); }
    float ex = (lane < 40) ? expf(val - m) : 0.f;
    float s = ex;
    #pragma unroll
    for (int o = 32; o > 0; o >>= 1) s += __shfl_xor(s, o);
    if (lane < 40) out[(size_t)c * 40 + lane] = val - m - logf(s);
}

// ---------------- launcher ----------------

extern "C" void kernel_launch(void* const* d_in, const int* in_sizes, int n_in,
                              void* d_out, int out_size, void* d_ws, size_t ws_size,
                              hipStream_t stream) {
    const float* x  = (const float*)d_in[0];
    const int*   ei = (const int*)d_in[1];
    const float* W1 = (const float*)d_in[2];
    const float* b1 = (const float*)d_in[3];
    const float* W2 = (const float*)d_in[4];
    const float* b2 = (const float*)d_in[5];
    float* out = (float*)d_out;

    int N = in_sizes[0] / 512;   // 100000
    int E = in_sizes[1] / 2;     // 3200000

    char* p = (char*)d_ws;
    auto carve = [&](size_t bytes) -> char* {
        char* q = p;
        p += (bytes + 1023) & ~(size_t)1023;
        return q;
    };
    float* dinv   = (float*)carve((size_t)N * 4);
    int*   cnt    = (int*)carve((size_t)N * 4);
    int*   colptr = (int*)carve(((size_t)N + 1) * 4);
    int*   fillc  = (int*)carve((size_t)N * 4);
    int*   bsum   = (int*)carve(1024 * 4);
    int*   eidx   = (int*)carve((size_t)E * 4);
    unsigned short* w1t = (unsigned short*)carve((size_t)256 * 512 * 2);
    unsigned short* xs  = (unsigned short*)carve((size_t)N * 256 * 2);   // 51.2 MB
    unsigned short* h   = (unsigned short*)carve((size_t)N * 256 * 2);   // 51.2 MB
    unsigned short* t2p = (unsigned short*)carve((size_t)N * 64 * 2);    // 12.8 MB

    hipMemsetAsync(cnt,   0, (size_t)N * 4, stream);
    hipMemsetAsync(fillc, 0, (size_t)N * 4, stream);

    int eb = (E + 255) / 256;
    int nb = (N + 511) / 512;

    count_kernel<<<eb, 256, 0, stream>>>(ei, cnt, E);
    scanA_kernel<<<nb, 256, 0, stream>>>(cnt, dinv, colptr, bsum, N);
    scanB_kernel<<<1, 256, 0, stream>>>(bsum, nb);
    scanC_kernel<<<nb, 256, 0, stream>>>(colptr, bsum, N, E);
    fill_kernel<<<eb, 256, 0, stream>>>(ei, colptr, fillc, eidx, E);
    convert_w1_kernel<<<512, 256, 0, stream>>>(W1, w1t);

    int mb = (N + 63) / 64;
    gemm1_kernel<<<mb, 256, 0, stream>>>(x, w1t, dinv, xs, N);
    spmm1_kernel<<<(N + 3) / 4, 256, 0, stream>>>(xs, colptr, eidx, dinv, b1, h, N);
    gemm2_kernel<<<(N + 31) / 32, 320, 0, stream>>>(h, W2, dinv, t2p, N);
    spmm2_kernel<<<(N + 3) / 4, 256, 0, stream>>>(t2p, colptr, eidx, dinv, b2, out, N);
}

// Round 5
// 949.227 us; speedup vs baseline: 1.6727x; 1.1065x over previous
//
#include <hip/hip_runtime.h>
#include <math.h>

typedef __attribute__((ext_vector_type(8))) short short8;
typedef __attribute__((ext_vector_type(4))) float f32x4;

static __device__ __forceinline__ unsigned short f2bf(float f) {
    unsigned int u = __float_as_uint(f);
    unsigned int r = (u + 0x7FFFu + ((u >> 16) & 1u)) >> 16;
    return (unsigned short)r;
}
static __device__ __forceinline__ float b2f(unsigned short s) {
    return __uint_as_float(((unsigned int)s) << 16);
}

// ---------------- graph build ----------------

__global__ void count_kernel(const int* __restrict__ ei, int* __restrict__ cnt, int E) {
    int e = blockIdx.x * 256 + threadIdx.x;
    if (e < E) atomicAdd(&cnt[ei[E + e]], 1);
}

__global__ void scanA_kernel(const int* __restrict__ cnt, float* __restrict__ dinv,
                             int* __restrict__ colptr, int* __restrict__ bsum, int n) {
    __shared__ int s[256];
    int b = blockIdx.x, t = threadIdx.x;
    int i = b * 512 + 2 * t;
    int c0 = (i     < n) ? cnt[i]     : 0;
    int c1 = (i + 1 < n) ? cnt[i + 1] : 0;
    if (i     < n) dinv[i]     = rsqrtf((float)(c0 + 1));
    if (i + 1 < n) dinv[i + 1] = rsqrtf((float)(c1 + 1));
    int v = c0 + c1;
    s[t] = v;
    __syncthreads();
    #pragma unroll
    for (int o = 1; o < 256; o <<= 1) {
        int x = (t >= o) ? s[t - o] : 0;
        __syncthreads();
        s[t] += x;
        __syncthreads();
    }
    int excl = s[t] - v;
    if (i     < n) colptr[i]     = excl;
    if (i + 1 < n) colptr[i + 1] = excl + c0;
    if (t == 255) bsum[b] = s[t];
}

__global__ void scanB_kernel(int* bsum, int nb) {
    __shared__ int s[256];
    int t = threadIdx.x;
    int v = (t < nb) ? bsum[t] : 0;
    s[t] = v;
    __syncthreads();
    #pragma unroll
    for (int o = 1; o < 256; o <<= 1) {
        int x = (t >= o) ? s[t - o] : 0;
        __syncthreads();
        s[t] += x;
        __syncthreads();
    }
    if (t < nb) bsum[t] = s[t] - v;
}

__global__ void scanC_kernel(int* __restrict__ colptr, const int* __restrict__ bsum,
                             int n, int E) {
    int b = blockIdx.x, t = threadIdx.x;
    int off = bsum[b];
    int i = b * 512 + 2 * t;
    if (i     < n) colptr[i]     += off;
    if (i + 1 < n) colptr[i + 1] += off;
    if (b == 0 && t == 0) colptr[n] = E;
}

__global__ void fill_kernel(const int* __restrict__ ei, const int* __restrict__ colptr,
                            int* __restrict__ fillc, int* __restrict__ eidx, int E) {
    int e = blockIdx.x * 256 + threadIdx.x;
    if (e < E) {
        int r = ei[e];
        int c = ei[E + e];
        int pos = colptr[c] + atomicAdd(&fillc[c], 1);
        eidx[pos] = r;
    }
}

// W1 [512][256] -> w1t [256][512] bf16 ; W2 [256][40] -> w2t [64][256] bf16 (pad 0)
__global__ void prep_w_kernel(const float* __restrict__ W1, const float* __restrict__ W2,
                              unsigned short* __restrict__ w1t, unsigned short* __restrict__ w2t) {
    int id = blockIdx.x * 256 + threadIdx.x;
    if (id < 512 * 256) {
        int k = id >> 8, n = id & 255;
        w1t[(size_t)n * 512 + k] = f2bf(W1[id]);
    } else {
        int id2 = id - 512 * 256;
        if (id2 < 64 * 256) {
            int n = id2 >> 8, k = id2 & 255;
            w2t[id2] = (n < 40) ? f2bf(W2[k * 40 + n]) : (unsigned short)0;
        }
    }
}

// ---------------- layer 1 GEMM (bf16 MFMA, fused fp32->bf16, double-buffered) ----
// xs = bf16((x @ W1) * dinv[row]). Tile 64x256, BK=32, 4 waves x (4x4 16x16x32).
// LDS rows padded to 40 shorts. Reg-prefetch next K-chunk; 1 barrier/iter.

__global__ __launch_bounds__(256) void gemm1_kernel(const float* __restrict__ x,
                                                    const unsigned short* __restrict__ w1t,
                                                    const float* __restrict__ dinv,
                                                    unsigned short* __restrict__ xs, int M) {
    __shared__ unsigned short As[2][64 * 40];
    __shared__ unsigned short Bs[2][256 * 40];
    int t = threadIdx.x;
    int m0 = blockIdx.x * 64;
    int lane = t & 63, wv = t >> 6;
    int wn = wv * 64;
    int lm = lane & 15, q = lane >> 4;

    int ra = t >> 2, kc = (t & 3) * 8;
    int am = m0 + ra; if (am >= M) am = M - 1;
    const float* Ap = x + (size_t)am * 512 + kc;
    const unsigned short* Bp = w1t + (size_t)ra * 512 + kc;

    f32x4 acc[4][4];
    f32x4 z = {0.f, 0.f, 0.f, 0.f};
    #pragma unroll
    for (int i = 0; i < 4; i++)
        #pragma unroll
        for (int j = 0; j < 4; j++) acc[i][j] = z;

    // prologue: k=0 chunk
    float4 a0 = *(const float4*)(Ap + 0);
    float4 a1 = *(const float4*)(Ap + 4);
    uint4 b0 = *(const uint4*)(Bp + 0);
    uint4 b1 = *(const uint4*)(Bp + 64 * 512);
    uint4 b2 = *(const uint4*)(Bp + 128 * 512);
    uint4 b3 = *(const uint4*)(Bp + 192 * 512);
    {
        uint4 ap;
        ap.x = (unsigned int)f2bf(a0.x) | ((unsigned int)f2bf(a0.y) << 16);
        ap.y = (unsigned int)f2bf(a0.z) | ((unsigned int)f2bf(a0.w) << 16);
        ap.z = (unsigned int)f2bf(a1.x) | ((unsigned int)f2bf(a1.y) << 16);
        ap.w = (unsigned int)f2bf(a1.z) | ((unsigned int)f2bf(a1.w) << 16);
        *(uint4*)&As[0][ra * 40 + kc] = ap;
        *(uint4*)&Bs[0][(ra +   0) * 40 + kc] = b0;
        *(uint4*)&Bs[0][(ra +  64) * 40 + kc] = b1;
        *(uint4*)&Bs[0][(ra + 128) * 40 + kc] = b2;
        *(uint4*)&Bs[0][(ra + 192) * 40 + kc] = b3;
    }
    __syncthreads();

    int buf = 0;
    for (int k0 = 0; k0 < 512; k0 += 32) {
        bool more = (k0 + 32) < 512;
        if (more) {
            a0 = *(const float4*)(Ap + k0 + 32);
            a1 = *(const float4*)(Ap + k0 + 36);
            b0 = *(const uint4*)(Bp + k0 + 32);
            b1 = *(const uint4*)(Bp + k0 + 32 + 64 * 512);
            b2 = *(const uint4*)(Bp + k0 + 32 + 128 * 512);
            b3 = *(const uint4*)(Bp + k0 + 32 + 192 * 512);
        }
        short8 af[4], bfr[4];
        #pragma unroll
        for (int i = 0; i < 4; i++)
            af[i] = *(const short8*)&As[buf][(i * 16 + lm) * 40 + q * 8];
        #pragma unroll
        for (int j = 0; j < 4; j++)
            bfr[j] = *(const short8*)&Bs[buf][(wn + j * 16 + lm) * 40 + q * 8];
        #pragma unroll
        for (int i = 0; i < 4; i++)
            #pragma unroll
            for (int j = 0; j < 4; j++)
                acc[i][j] = __builtin_amdgcn_mfma_f32_16x16x32_bf16(af[i], bfr[j], acc[i][j], 0, 0, 0);
        if (more) {
            uint4 ap;
            ap.x = (unsigned int)f2bf(a0.x) | ((unsigned int)f2bf(a0.y) << 16);
            ap.y = (unsigned int)f2bf(a0.z) | ((unsigned int)f2bf(a0.w) << 16);
            ap.z = (unsigned int)f2bf(a1.x) | ((unsigned int)f2bf(a1.y) << 16);
            ap.w = (unsigned int)f2bf(a1.z) | ((unsigned int)f2bf(a1.w) << 16);
            int nb = buf ^ 1;
            *(uint4*)&As[nb][ra * 40 + kc] = ap;
            *(uint4*)&Bs[nb][(ra +   0) * 40 + kc] = b0;
            *(uint4*)&Bs[nb][(ra +  64) * 40 + kc] = b1;
            *(uint4*)&Bs[nb][(ra + 128) * 40 + kc] = b2;
            *(uint4*)&Bs[nb][(ra + 192) * 40 + kc] = b3;
            __syncthreads();
        }
        buf ^= 1;
    }

    #pragma unroll
    for (int i = 0; i < 4; i++) {
        #pragma unroll
        for (int r = 0; r < 4; r++) {
            int m = m0 + i * 16 + q * 4 + r;
            if (m < M) {
                float d = dinv[m];
                #pragma unroll
                for (int j = 0; j < 4; j++) {
                    int n = wn + j * 16 + lm;
                    xs[(size_t)m * 256 + n] = f2bf(acc[i][j][r] * d);
                }
            }
        }
    }
}

// ---------------- layer 1 aggregate ----------------

__global__ __launch_bounds__(256) void spmm1_kernel(const unsigned short* __restrict__ xs,
                                                    const int* __restrict__ colptr,
                                                    const int* __restrict__ eidx,
                                                    const float* __restrict__ dinv,
                                                    const float* __restrict__ b1,
                                                    unsigned short* __restrict__ h, int Nn) {
    int wid = threadIdx.x >> 6, lane = threadIdx.x & 63;
    int c = blockIdx.x * 4 + wid;
    if (c >= Nn) return;
    const uint2* base = (const uint2*)xs;
    uint2 sv = base[(size_t)c * 64 + lane];
    float a0 = __uint_as_float(sv.x << 16);
    float a1 = __uint_as_float(sv.x & 0xFFFF0000u);
    float a2 = __uint_as_float(sv.y << 16);
    float a3 = __uint_as_float(sv.y & 0xFFFF0000u);
    int j = colptr[c], jend = colptr[c + 1];
    for (; j + 3 < jend; j += 4) {
        uint2 v0 = base[(size_t)eidx[j    ] * 64 + lane];
        uint2 v1 = base[(size_t)eidx[j + 1] * 64 + lane];
        uint2 v2 = base[(size_t)eidx[j + 2] * 64 + lane];
        uint2 v3 = base[(size_t)eidx[j + 3] * 64 + lane];
        a0 += __uint_as_float(v0.x << 16) + __uint_as_float(v1.x << 16)
            + __uint_as_float(v2.x << 16) + __uint_as_float(v3.x << 16);
        a1 += __uint_as_float(v0.x & 0xFFFF0000u) + __uint_as_float(v1.x & 0xFFFF0000u)
            + __uint_as_float(v2.x & 0xFFFF0000u) + __uint_as_float(v3.x & 0xFFFF0000u);
        a2 += __uint_as_float(v0.y << 16) + __uint_as_float(v1.y << 16)
            + __uint_as_float(v2.y << 16) + __uint_as_float(v3.y << 16);
        a3 += __uint_as_float(v0.y & 0xFFFF0000u) + __uint_as_float(v1.y & 0xFFFF0000u)
            + __uint_as_float(v2.y & 0xFFFF0000u) + __uint_as_float(v3.y & 0xFFFF0000u);
    }
    for (; j < jend; j++) {
        uint2 v0 = base[(size_t)eidx[j] * 64 + lane];
        a0 += __uint_as_float(v0.x << 16);
        a1 += __uint_as_float(v0.x & 0xFFFF0000u);
        a2 += __uint_as_float(v0.y << 16);
        a3 += __uint_as_float(v0.y & 0xFFFF0000u);
    }
    float d = dinv[c];
    float4 bb = ((const float4*)b1)[lane];
    float f0 = fmaxf(a0 * d + bb.x, 0.f);
    float f1 = fmaxf(a1 * d + bb.y, 0.f);
    float f2 = fmaxf(a2 * d + bb.z, 0.f);
    float f3 = fmaxf(a3 * d + bb.w, 0.f);
    uint2 p;
    p.x = (unsigned int)f2bf(f0) | ((unsigned int)f2bf(f1) << 16);
    p.y = (unsigned int)f2bf(f2) | ((unsigned int)f2bf(f3) << 16);
    *(uint2*)(h + (size_t)c * 256 + 4 * lane) = p;
}

// ---------------- layer 2 GEMM (bf16 MFMA): t2p = bf16((h @ W2) * dinv), stride 64 --
// Tile 64(m) x 64(n), full K=256 in LDS, one barrier. 4 waves; wave w = rows w*16..+15.

__global__ __launch_bounds__(256) void gemm2_kernel(const unsigned short* __restrict__ h,
                                                    const unsigned short* __restrict__ w2t,
                                                    const float* __restrict__ dinv,
                                                    unsigned short* __restrict__ t2p, int M) {
    __shared__ unsigned short As[64 * 264];
    __shared__ unsigned short Bs[64 * 264];
    int t = threadIdx.x;
    int m0 = blockIdx.x * 64;
    int lane = t & 63, wv = t >> 6;
    int lm = lane & 15, q = lane >> 4;

    // full 64x256 tile: 2048 chunks of 8 shorts
    #pragma unroll
    for (int i = 0; i < 8; i++) {
        int c = t + i * 256;                 // 0..2047
        int row = c >> 5, col = (c & 31) * 8;   // row 0..63, col 0..248
        int m = m0 + row; if (m >= M) m = M - 1;
        uint4 av = *(const uint4*)(h + (size_t)m * 256 + col);
        *(uint4*)&As[row * 264 + col] = av;
        uint4 bv = *(const uint4*)(w2t + (size_t)row * 256 + col);
        *(uint4*)&Bs[row * 264 + col] = bv;
    }
    __syncthreads();

    f32x4 acc[4];
    f32x4 z = {0.f, 0.f, 0.f, 0.f};
    #pragma unroll
    for (int j = 0; j < 4; j++) acc[j] = z;

    #pragma unroll
    for (int k0 = 0; k0 < 256; k0 += 32) {
        short8 af = *(const short8*)&As[(wv * 16 + lm) * 264 + k0 + q * 8];
        #pragma unroll
        for (int j = 0; j < 4; j++) {
            short8 bf = *(const short8*)&Bs[(j * 16 + lm) * 264 + k0 + q * 8];
            acc[j] = __builtin_amdgcn_mfma_f32_16x16x32_bf16(af, bf, acc[j], 0, 0, 0);
        }
    }

    #pragma unroll
    for (int r = 0; r < 4; r++) {
        int m = m0 + wv * 16 + q * 4 + r;
        if (m < M) {
            float d = dinv[m];
            #pragma unroll
            for (int j = 0; j < 4; j++)
                t2p[(size_t)m * 64 + j * 16 + lm] = f2bf(acc[j][r] * d);
        }
    }
}

// ---------------- layer 2 aggregate + bias + log_softmax ----------------

__global__ __launch_bounds__(256) void spmm2_kernel(const unsigned short* __restrict__ t2p,
                                                    const int* __restrict__ colptr,
                                                    const int* __restrict__ eidx,
                                                    const float* __restrict__ dinv,
                                                    const float* __restrict__ b2,
                                                    float* __restrict__ out, int Nn) {
    int wid = threadIdx.x >> 6, lane = threadIdx.x & 63;
    int c = blockIdx.x * 4 + wid;
    if (c >= Nn) return;
    float acc = b2f(t2p[(size_t)c * 64 + lane]);
    int j = colptr[c], jend = colptr[c + 1];
    float a0 = 0.f, a1 = 0.f, a2 = 0.f, a3 = 0.f;
    for (; j + 7 < jend; j += 8) {
        float u0 = b2f(t2p[(size_t)eidx[j    ] * 64 + lane]);
        float u1 = b2f(t2p[(size_t)eidx[j + 1] * 64 + lane]);
        float u2 = b2f(t2p[(size_t)eidx[j + 2] * 64 + lane]);
        float u3 = b2f(t2p[(size_t)eidx[j + 3] * 64 + lane]);
        float u4 = b2f(t2p[(size_t)eidx[j + 4] * 64 + lane]);
        float u5 = b2f(t2p[(size_t)eidx[j + 5] * 64 + lane]);
        float u6 = b2f(t2p[(size_t)eidx[j + 6] * 64 + lane]);
        float u7 = b2f(t2p[(size_t)eidx[j + 7] * 64 + lane]);
        a0 += u0 + u4; a1 += u1 + u5; a2 += u2 + u6; a3 += u3 + u7;
    }
    for (; j < jend; j++) a0 += b2f(t2p[(size_t)eidx[j] * 64 + lane]);
    acc += (a0 + a1) + (a2 + a3);
    float val = (lane < 40) ? (acc * dinv[c] + b2[lane]) : -INFINITY;
    float m = val;
    #pragma unroll
    for (int o = 32; o > 0; o >>= 1) { float z = __shfl_xor(m, o); m = fmaxf(m, z); }
    float ex = (lane < 40) ? expf(val - m) : 0.f;
    float s = ex;
    #pragma unroll
    for (int o = 32; o > 0; o >>= 1) s += __shfl_xor(s, o);
    if (lane < 40) out[(size_t)c * 40 + lane] = val - m - logf(s);
}

// ---------------- launcher ----------------

extern "C" void kernel_launch(void* const* d_in, const int* in_sizes, int n_in,
                              void* d_out, int out_size, void* d_ws, size_t ws_size,
                              hipStream_t stream) {
    const float* x  = (const float*)d_in[0];
    const int*   ei = (const int*)d_in[1];
    const float* W1 = (const float*)d_in[2];
    const float* b1 = (const float*)d_in[3];
    const float* W2 = (const float*)d_in[4];
    const float* b2 = (const float*)d_in[5];
    float* out = (float*)d_out;

    int N = in_sizes[0] / 512;   // 100000
    int E = in_sizes[1] / 2;     // 3200000

    char* p = (char*)d_ws;
    auto carve = [&](size_t bytes) -> char* {
        char* q = p;
        p += (bytes + 1023) & ~(size_t)1023;
        return q;
    };
    float* dinv   = (float*)carve((size_t)N * 4);
    int*   cnt    = (int*)carve((size_t)N * 4);
    int*   colptr = (int*)carve(((size_t)N + 1) * 4);
    int*   fillc  = (int*)carve((size_t)N * 4);
    int*   bsum   = (int*)carve(1024 * 4);
    int*   eidx   = (int*)carve((size_t)E * 4);
    unsigned short* w1t = (unsigned short*)carve((size_t)256 * 512 * 2);
    unsigned short* w2t = (unsigned short*)carve((size_t)64 * 256 * 2);
    unsigned short* xs  = (unsigned short*)carve((size_t)N * 256 * 2);
    unsigned short* h   = (unsigned short*)carve((size_t)N * 256 * 2);
    unsigned short* t2p = (unsigned short*)carve((size_t)N * 64 * 2);

    hipMemsetAsync(cnt,   0, (size_t)N * 4, stream);
    hipMemsetAsync(fillc, 0, (size_t)N * 4, stream);

    int eb = (E + 255) / 256;
    int nb = (N + 511) / 512;

    count_kernel<<<eb, 256, 0, stream>>>(ei, cnt, E);
    scanA_kernel<<<nb, 256, 0, stream>>>(cnt, dinv, colptr, bsum, N);
    scanB_kernel<<<1, 256, 0, stream>>>(bsum, nb);
    scanC_kernel<<<nb, 256, 0, stream>>>(colptr, bsum, N, E);
    fill_kernel<<<eb, 256, 0, stream>>>(ei, colptr, fillc, eidx, E);
    prep_w_kernel<<<576, 256, 0, stream>>>(W1, W2, w1t, w2t);

    int mb = (N + 63) / 64;
    gemm1_kernel<<<mb, 256, 0, stream>>>(x, w1t, dinv, xs, N);
    spmm1_kernel<<<(N + 3) / 4, 256, 0, stream>>>(xs, colptr, eidx, dinv, b1, h, N);
    gemm2_kernel<<<mb, 256, 0, stream>>>(h, w2t, dinv, t2p, N);
    spmm2_kernel<<<(N + 3) / 4, 256, 0, stream>>>(t2p, colptr, eidx, dinv, b2, out, N);
}